// Round 3
// baseline (2007.798 us; speedup 1.0000x reference)
//
#include <hip/hip_runtime.h>
#include <stdint.h>

#define T_LEN 4096
#define NHID  128

typedef float    f32x4 __attribute__((ext_vector_type(4)));
typedef _Float16 f16x4 __attribute__((ext_vector_type(4)));
typedef _Float16 f16x8 __attribute__((ext_vector_type(8)));
typedef __fp16   h16x2 __attribute__((ext_vector_type(2)));
typedef uint32_t u32x2 __attribute__((ext_vector_type(2)));
typedef uint32_t u32x4 __attribute__((ext_vector_type(4)));

struct P2 { h16x2 p0, p1; };
struct P4 { h16x2 p0, p1, p2, p3; };
struct U22 { u32x2 a, b; };

static __device__ __forceinline__ f16x4 cvt_f16x4(f32x4 v) {
    P2 p;
    p.p0 = __builtin_amdgcn_cvt_pkrtz(v.x, v.y);
    p.p1 = __builtin_amdgcn_cvt_pkrtz(v.z, v.w);
    return __builtin_bit_cast(f16x4, p);
}
static __device__ __forceinline__ f16x8 cvt_f16x8(f32x4 a, f32x4 b) {
    P4 p;
    p.p0 = __builtin_amdgcn_cvt_pkrtz(a.x, a.y);
    p.p1 = __builtin_amdgcn_cvt_pkrtz(a.z, a.w);
    p.p2 = __builtin_amdgcn_cvt_pkrtz(b.x, b.y);
    p.p3 = __builtin_amdgcn_cvt_pkrtz(b.z, b.w);
    return __builtin_bit_cast(f16x8, p);
}
static __device__ __forceinline__ f32x4 relu4(f32x4 v) {
    v.x = fmaxf(v.x, 0.f); v.y = fmaxf(v.y, 0.f);
    v.z = fmaxf(v.z, 0.f); v.w = fmaxf(v.w, 0.f);
    return v;
}
// pack f32x4 -> 4 f16 (RTZ) then relu in f16 (identical result to relu-then-pack)
static __device__ __forceinline__ u32x2 relu_pk(f32x4 v) {
    P2 p;
    p.p0 = __builtin_amdgcn_cvt_pkrtz(v.x, v.y);
    p.p1 = __builtin_amdgcn_cvt_pkrtz(v.z, v.w);
    f16x4 h = __builtin_bit_cast(f16x4, p);
    const f16x4 z = {};
    h = __builtin_elementwise_max(h, z);   // 2x v_pk_max_f16
    return __builtin_bit_cast(u32x2, h);
}
static __device__ __forceinline__ f32x4 unpk4(u32x2 q) {
    f16x4 h = __builtin_bit_cast(f16x4, q);
    f32x4 r = { (float)h.x, (float)h.y, (float)h.z, (float)h.w };
    return r;
}
#define MFMA32(a, b, c) __builtin_amdgcn_mfma_f32_16x16x32_f16((a), (b), (c), 0, 0, 0)
#define MFMA16(a, b, c) __builtin_amdgcn_mfma_f32_16x16x16f16((a), (b), (c), 0, 0, 0)

// LDS-only barrier. (The waitcnt pass may add conservative vmcnt waits around
// inline asm; on the compute wave vmcnt is ALWAYS 0 -> free by construction.)
#define LDS_BARRIER() asm volatile("s_waitcnt lgkmcnt(0)\n\ts_barrier" ::: "memory")

// global -> LDS direct DMA, 16 B/lane (lane i lands at ldsbase + 16*i)
#define GLL16(gp, lp)                                                         \
    __builtin_amdgcn_global_load_lds(                                         \
        (const __attribute__((address_space(1))) void*)(gp),                  \
        (__attribute__((address_space(3))) void*)(lp), 16, 0, 0)

// Layouts (per batch group g; lane l=(u<<4)|c, batch=16g+c):
//   phiC (C-frag / h / xp storage): unit(m,u,i) = 16m + 4u + i
//   phiB (W1h K-axis gather):  unit(kt,u,j) = 64*(j>>2) + 16kt + 4u + (j&3)
// B-frag[kt] of step t+1 == concat(pk[kt], pk[kt+4]) of step t's packed C
// output -> recurrence needs NO cross-lane movement.
//
// xp (packed f16, in d_out): xp[(g*T + t)*1024 + q*256 + 4l + 0..3] (u32)
//   q-th u32x4 = { pk[2q], pk[2q+1] }  (m = 2q, 2q+1)
// hg (packed f16, in d_ws):  hg[(g*T + t)*1024 + q*256 + 4l + 0..3] (u32)
//   q-th u32x4 = { pk[2q], pk[2q+1] }

// -------------------------------------------------------------------------
// Kernel 0: xp = input . W1x^T + b1 (K=32 MFMA), packed to f16.
// Grid 1024 = g*256 + tc, block 64, 16 t per block.
// -------------------------------------------------------------------------
__global__ __launch_bounds__(64, 2)
void xproj_kernel(const float* __restrict__ input, const float* __restrict__ W1,
                  const float* __restrict__ b1, uint32_t* __restrict__ xp) {
    const int bid = blockIdx.x;
    const int g   = bid >> 8;          // 0..3
    const int tc  = bid & 255;         // 0..255
    const int l   = threadIdx.x;
    const int c   = l & 15, u = l >> 4;

    // A-fragments of W1x (cols 128..255): A[m=c][k=32j+8u+0..7]
    f16x8 wa[8][4];
#pragma unroll
    for (int m = 0; m < 8; ++m) {
        const float* wr = W1 + (16 * m + c) * 256 + 128 + 8 * u;
#pragma unroll
        for (int j = 0; j < 4; ++j)
            wa[m][j] = cvt_f16x8(*(const f32x4*)(wr + 32 * j),
                                 *(const f32x4*)(wr + 32 * j + 4));
    }
    f32x4 bi[8];
#pragma unroll
    for (int m = 0; m < 8; ++m) bi[m] = *(const f32x4*)(b1 + 16 * m + 4 * u);

    const int t0 = tc * 16;
    const float* ip0 = input + (size_t)(16 * g + c) * T_LEN * NHID + 8 * u;
    uint32_t* xp0 = xp + ((size_t)g * T_LEN) * 1024 + 4 * l;
#pragma unroll 1
    for (int tt = 0; tt < 16; ++tt) {
        const int t = t0 + tt;
        const float* ip = ip0 + (size_t)t * NHID;
        f16x8 xb[4];
#pragma unroll
        for (int j = 0; j < 4; ++j)
            xb[j] = cvt_f16x8(*(const f32x4*)(ip + 32 * j),
                              *(const f32x4*)(ip + 32 * j + 4));
        u32x2 pk[8];
#pragma unroll
        for (int m = 0; m < 8; ++m) {
            f32x4 a = bi[m];
#pragma unroll
            for (int j = 0; j < 4; ++j) a = MFMA32(wa[m][j], xb[j], a);
            pk[m] = __builtin_bit_cast(u32x2, cvt_f16x4(a));
        }
        uint32_t* xpt = xp0 + (size_t)t * 1024;
#pragma unroll
        for (int q = 0; q < 4; ++q) {
            U22 qq = { pk[2 * q], pk[2 * q + 1] };
            *(u32x4*)(xpt + q * 256) = __builtin_bit_cast(u32x4, qq);
        }
    }
}

// -------------------------------------------------------------------------
// Kernel 1: recurrence. Grid 4 (g), block 128 = 2 waves.
//   Wave 0 (compute): ZERO vmem instructions after W1 init. h register-
//     resident; xp read from LDS ring (4x ds_read_b128/step), h written to
//     LDS ring (4x ds_write_b128/step). Only lgkm waits -> no vmem stalls
//     possible, by construction.
//   Wave 1 (service): DMAs xp chunk j+1 into the LDS ring with
//     global_load_lds (16x 1KB per 4-step chunk), drains h chunk j-1 from
//     LDS to HBM (16 ds_read_b128 + 16 global_store_dwordx4), then
//     vmcnt(0). Its ~700cy latency exposure amortizes over 4 steps and
//     sits under the compute wave's chunk time.
// LDS: xp ring 2x16KB + h ring 2x16KB = 64 KB. One barrier per 4 steps;
// both waves execute exactly 1025 barriers.
// -------------------------------------------------------------------------
__global__ __launch_bounds__(128, 1)
void rec_kernel(const uint32_t* __restrict__ xp, const float* __restrict__ W1,
                uint32_t* __restrict__ hg) {
    const int g = blockIdx.x;
    const int w = threadIdx.x >> 6;
    const int l = threadIdx.x & 63;
    const int c = l & 15, u = l >> 4;

    __shared__ uint32_t xpring[2 * 4096];  // 32 KB: [slot][sp*4+q][4l+i]
    __shared__ uint32_t hring [2 * 4096];  // 32 KB: same layout

    const uint32_t* xpl = xp + ((size_t)g * T_LEN) * 1024 + 4 * l;  // per-lane

    if (w == 1) {
        // prologue: DMA chunk 0 into xp slot 0
#pragma unroll
        for (int i = 0; i < 16; ++i)
            GLL16(xpl + i * 256, &xpring[i * 256]);
        asm volatile("s_waitcnt vmcnt(0)" ::: "memory");
    }
    LDS_BARRIER();   // barrier #0 (both waves)

    if (w == 0) {
        // ---- compute wave ----
        // W1h A-frags, K-axis permuted by phiB:
        //   waH[m][kt] elem j = W1h[16m+c][ 64*(j>>2) + 16kt + 4u + (j&3) ]
        f16x8 waH[8][4];
#pragma unroll
        for (int m = 0; m < 8; ++m) {
            const float* wr = W1 + (16 * m + c) * 256;   // h-part: cols 0..127
#pragma unroll
            for (int kt = 0; kt < 4; ++kt)
                waH[m][kt] = cvt_f16x8(*(const f32x4*)(wr + 16 * kt + 4 * u),
                                       *(const f32x4*)(wr + 64 + 16 * kt + 4 * u));
        }

        // h_0 = 0
        f16x8 bf[4];
#pragma unroll
        for (int kt = 0; kt < 4; ++kt) {
            const u32x4 z = {0, 0, 0, 0};
            bf[kt] = __builtin_bit_cast(f16x8, z);
        }

#pragma unroll 1
        for (int j = 0; j < T_LEN / 4; ++j) {
            const uint32_t* xs = &xpring[(j & 1) * 4096];
            uint32_t*       hs = &hring [(j & 1) * 4096];
#pragma unroll
            for (int sp = 0; sp < 4; ++sp) {
                // xp slice for step t = 4j+sp (4x ds_read_b128)
                u32x4 xq[4];
#pragma unroll
                for (int q = 0; q < 4; ++q)
                    xq[q] = *(const u32x4*)&xs[(sp * 4 + q) * 256 + 4 * l];
                f32x4 acc[8];
#pragma unroll
                for (int q = 0; q < 4; ++q) {
                    u32x2 e0 = { xq[q].x, xq[q].y };
                    u32x2 e1 = { xq[q].z, xq[q].w };
                    acc[2 * q]     = unpk4(e0);
                    acc[2 * q + 1] = unpk4(e1);
                }
                // m interleave 0,4,1,5,...: acc[0],acc[4] (-> bf[0]) retire
                // earliest in the last kt round.
#pragma unroll
                for (int kt = 0; kt < 4; ++kt) {
#pragma unroll
                    for (int i = 0; i < 8; ++i) {
                        const int m = ((i & 1) << 2) | (i >> 1);
                        acc[m] = MFMA32(waH[m][kt], bf[kt], acc[m]);
                    }
                }
                // pack h_{t+1}; B-frags for step t+2 are register concats
                u32x2 pk[8];
#pragma unroll
                for (int kk = 0; kk < 4; ++kk) {
                    pk[kk]     = relu_pk(acc[kk]);
                    pk[kk + 4] = relu_pk(acc[kk + 4]);
                    U22 qq = { pk[kk], pk[kk + 4] };
                    bf[kk] = __builtin_bit_cast(f16x8, qq);
                }
                // h_{t+1} -> LDS ring (4x ds_write_b128)
#pragma unroll
                for (int q = 0; q < 4; ++q) {
                    U22 qq = { pk[2 * q], pk[2 * q + 1] };
                    *(u32x4*)&hs[(sp * 4 + q) * 256 + 4 * l] =
                        __builtin_bit_cast(u32x4, qq);
                }
            }
            LDS_BARRIER();
        }
    } else {
        // ---- service wave ----
        uint32_t* hgp = hg + ((size_t)g * T_LEN) * 1024 + 4 * l;
#pragma unroll 1
        for (int j = 0; j < T_LEN / 4; ++j) {
            // DMA xp chunk j+1 into slot (j+1)&1 (consumed by compute at j+1;
            // slot was last read by compute during chunk j-1 -> free).
            if (j + 1 < T_LEN / 4) {
                const uint32_t* gsrc = xpl + (size_t)(j + 1) * 4096;
                uint32_t* ldst = &xpring[((j + 1) & 1) * 4096];
#pragma unroll
                for (int i = 0; i < 16; ++i)
                    GLL16(gsrc + i * 256, &ldst[i * 256]);
            }
            // drain h of chunk j-1 (published by barrier at end of j-1)
            if (j > 0) {
                const uint32_t* hl = &hring[((j - 1) & 1) * 4096];
                u32x4 v[16];
#pragma unroll
                for (int i = 0; i < 16; ++i)
                    v[i] = *(const u32x4*)&hl[i * 256 + 4 * l];
                uint32_t* hp = hgp + (size_t)((j - 1) * 4) * 1024;
#pragma unroll
                for (int i = 0; i < 16; ++i)
                    *(u32x4*)(hp + i * 256) = v[i];  // i*256 == sp*1024+q*256
            }
            // ensure chunk j+1's xp has landed in LDS before the barrier
            asm volatile("s_waitcnt vmcnt(0)" ::: "memory");
            LDS_BARRIER();
        }
        // final: drain h of chunk 1023 (slot 1); last barrier published it
        {
            const int c0 = T_LEN / 4 - 1;
            const uint32_t* hl = &hring[(c0 & 1) * 4096];
            u32x4 v[16];
#pragma unroll
            for (int i = 0; i < 16; ++i)
                v[i] = *(const u32x4*)&hl[i * 256 + 4 * l];
            uint32_t* hp = hgp + (size_t)(c0 * 4) * 1024;
#pragma unroll
            for (int i = 0; i < 16; ++i)
                *(u32x4*)(hp + i * 256) = v[i];
        }
    }
}

// -------------------------------------------------------------------------
// Kernel 2: out[b,t,:] = relu(W2 . h_{t+1} + b2), K=16 MFMA.
// h fragments read verbatim (C-frag == B-frag for 16x16x16 under phiC).
// Grid 2048 = g*512 + tc, block 64, 8 t per block.
// -------------------------------------------------------------------------
__global__ __launch_bounds__(64, 2)
void out_kernel(const uint32_t* __restrict__ hg, const float* __restrict__ W2,
                const float* __restrict__ b2, float* __restrict__ out) {
    const int bid = blockIdx.x;
    const int g   = bid >> 9;
    const int tc  = bid & 511;
    const int l   = threadIdx.x;
    const int c   = l & 15, u = l >> 4;

    f16x4 wa[8][8];
#pragma unroll
    for (int m = 0; m < 8; ++m) {
        const float* wr = W2 + (16 * m + c) * 128 + 4 * u;
#pragma unroll
        for (int s = 0; s < 8; ++s)
            wa[m][s] = cvt_f16x4(*(const f32x4*)(wr + 16 * s));
    }
    f32x4 bi[8];
#pragma unroll
    for (int m = 0; m < 8; ++m) bi[m] = *(const f32x4*)(b2 + 16 * m + 4 * u);

    const int t0 = tc * 8;
    const uint32_t* hg0 = hg + ((size_t)g * T_LEN) * 1024 + 4 * l;
    float* op0 = out + (size_t)(16 * g + c) * T_LEN * NHID + 4 * u;
#pragma unroll 1
    for (int tt = 0; tt < 8; ++tt) {
        const int t = t0 + tt;
        const uint32_t* hp = hg0 + (size_t)t * 1024;
        f16x4 hb[8];
#pragma unroll
        for (int s = 0; s < 8; ++s)
            hb[s] = __builtin_bit_cast(f16x4,
                        *(const u32x2*)(hp + (s >> 1) * 256 + (s & 1) * 2));
        f32x4 acc[8];
#pragma unroll
        for (int m = 0; m < 8; ++m) {
            f32x4 a = bi[m];
#pragma unroll
            for (int s = 0; s < 8; ++s) a = MFMA16(wa[m][s], hb[s], a);
            acc[m] = relu4(a);
        }
        float* op = op0 + (size_t)t * NHID;
#pragma unroll
        for (int m = 0; m < 8; ++m) *(f32x4*)(op + 16 * m) = acc[m];
    }
}

// -------------------------------------------------------------------------
extern "C" void kernel_launch(void* const* d_in, const int* in_sizes, int n_in,
                              void* d_out, int out_size, void* d_ws, size_t ws_size,
                              hipStream_t stream) {
    const float* input = (const float*)d_in[0];  // (64, 4096, 128) f32
    const float* W1    = (const float*)d_in[1];  // (128, 256) f32
    const float* b1    = (const float*)d_in[2];  // (128,) f32
    const float* W2    = (const float*)d_in[3];  // (128, 128) f32
    const float* b2    = (const float*)d_in[4];  // (128,) f32
    float*    out = (float*)d_out;
    uint32_t* xpb = (uint32_t*)d_out;            // xp scratch (64 MiB, f16-
                                                 // packed) in d_out; fully
                                                 // consumed by rec before
                                                 // out_kernel overwrites
    uint32_t* hgb = (uint32_t*)d_ws;             // h stream: 64 MiB in d_ws

    xproj_kernel<<<1024, 64, 0, stream>>>(input, W1, b1, xpb);
    rec_kernel  <<<4,   128, 0, stream>>>(xpb, W1, hgb);
    out_kernel  <<<2048, 64, 0, stream>>>(hgb, W2, b2, out);
}

// Round 4
// 1153.842 us; speedup vs baseline: 1.7401x; 1.7401x over previous
//
#include <hip/hip_runtime.h>
#include <stdint.h>

#define T_LEN 4096
#define NHID  128

typedef float    f32x4 __attribute__((ext_vector_type(4)));
typedef _Float16 f16x4 __attribute__((ext_vector_type(4)));
typedef _Float16 f16x8 __attribute__((ext_vector_type(8)));
typedef __fp16   h16x2 __attribute__((ext_vector_type(2)));
typedef uint32_t u32x2 __attribute__((ext_vector_type(2)));
typedef uint32_t u32x4 __attribute__((ext_vector_type(4)));

struct P2 { h16x2 p0, p1; };
struct P4 { h16x2 p0, p1, p2, p3; };
struct U22 { u32x2 a, b; };

static __device__ __forceinline__ f16x4 cvt_f16x4(f32x4 v) {
    P2 p;
    p.p0 = __builtin_amdgcn_cvt_pkrtz(v.x, v.y);
    p.p1 = __builtin_amdgcn_cvt_pkrtz(v.z, v.w);
    return __builtin_bit_cast(f16x4, p);
}
static __device__ __forceinline__ f16x8 cvt_f16x8(f32x4 a, f32x4 b) {
    P4 p;
    p.p0 = __builtin_amdgcn_cvt_pkrtz(a.x, a.y);
    p.p1 = __builtin_amdgcn_cvt_pkrtz(a.z, a.w);
    p.p2 = __builtin_amdgcn_cvt_pkrtz(b.x, b.y);
    p.p3 = __builtin_amdgcn_cvt_pkrtz(b.z, b.w);
    return __builtin_bit_cast(f16x8, p);
}
static __device__ __forceinline__ f32x4 relu4(f32x4 v) {
    v.x = fmaxf(v.x, 0.f); v.y = fmaxf(v.y, 0.f);
    v.z = fmaxf(v.z, 0.f); v.w = fmaxf(v.w, 0.f);
    return v;
}
// pack f32x4 -> 4 f16 (RTZ) then relu in f16 (identical result to relu-then-pack)
static __device__ __forceinline__ u32x2 relu_pk(f32x4 v) {
    P2 p;
    p.p0 = __builtin_amdgcn_cvt_pkrtz(v.x, v.y);
    p.p1 = __builtin_amdgcn_cvt_pkrtz(v.z, v.w);
    f16x4 h = __builtin_bit_cast(f16x4, p);
    const f16x4 z = {};
    h = __builtin_elementwise_max(h, z);   // 2x v_pk_max_f16
    return __builtin_bit_cast(u32x2, h);
}
static __device__ __forceinline__ f32x4 unpk4(u32x2 q) {
    f16x4 h = __builtin_bit_cast(f16x4, q);
    f32x4 r = { (float)h.x, (float)h.y, (float)h.z, (float)h.w };
    return r;
}
#define MFMA32(a, b, c) __builtin_amdgcn_mfma_f32_16x16x32_f16((a), (b), (c), 0, 0, 0)
#define MFMA16(a, b, c) __builtin_amdgcn_mfma_f32_16x16x16f16((a), (b), (c), 0, 0, 0)

// LDS-only barrier: drains LDS ops, leaves global (vmcnt) traffic in flight.
#define LDS_BARRIER() asm volatile("s_waitcnt lgkmcnt(0)\n\ts_barrier" ::: "memory")

// Layouts (per batch group g; lane l=(u<<4)|c, batch=16g+c):
//   phiC (C-frag / h / xp storage): unit(m,u,i) = 16m + 4u + i
//   phiB (W1h K-axis gather):  unit(kt,u,j) = 64*(j>>2) + 16kt + 4u + (j&3)
// B-frag[kt] of step t+1 == concat(pk[kt], pk[kt+4]) of step t's packed C
// output. NEW pairing: wave w owns m = {w, w+4}, so bf[w] is FULLY LOCAL
// (register concat); only 3 frags/step cross waves via LDS.
//
// xp (packed f16, in d_out): xp[(g*T+t)*1024 + q*256 + 4l + 0..3] (u32)
//   q-th u32x4 = { pk[q], pk[q+4] }
// hg (packed f16, in d_ws):  hg[(g*T+t)*1024 + q*256 + 4l + 0..3] (u32)
//   q-th u32x4 = { pk[q], pk[q+4] }   (h_{t+1} at index t)

// -------------------------------------------------------------------------
// Kernel 0: xp = input . W1x^T + b1 (K=32 MFMA), packed f16, paired layout.
// Grid 1024 = g*256 + tc, block 64, 16 t per block.
// -------------------------------------------------------------------------
__global__ __launch_bounds__(64, 2)
void xproj_kernel(const float* __restrict__ input, const float* __restrict__ W1,
                  const float* __restrict__ b1, uint32_t* __restrict__ xp) {
    const int bid = blockIdx.x;
    const int g   = bid >> 8;          // 0..3
    const int tc  = bid & 255;         // 0..255
    const int l   = threadIdx.x;
    const int c   = l & 15, u = l >> 4;

    // A-fragments of W1x (cols 128..255): A[m=c][k=32j+8u+0..7]
    f16x8 wa[8][4];
#pragma unroll
    for (int m = 0; m < 8; ++m) {
        const float* wr = W1 + (16 * m + c) * 256 + 128 + 8 * u;
#pragma unroll
        for (int j = 0; j < 4; ++j)
            wa[m][j] = cvt_f16x8(*(const f32x4*)(wr + 32 * j),
                                 *(const f32x4*)(wr + 32 * j + 4));
    }
    f32x4 bi[8];
#pragma unroll
    for (int m = 0; m < 8; ++m) bi[m] = *(const f32x4*)(b1 + 16 * m + 4 * u);

    const int t0 = tc * 16;
    const float* ip0 = input + (size_t)(16 * g + c) * T_LEN * NHID + 8 * u;
    uint32_t* xp0 = xp + ((size_t)g * T_LEN) * 1024 + 4 * l;
#pragma unroll 1
    for (int tt = 0; tt < 16; ++tt) {
        const int t = t0 + tt;
        const float* ip = ip0 + (size_t)t * NHID;
        f16x8 xb[4];
#pragma unroll
        for (int j = 0; j < 4; ++j)
            xb[j] = cvt_f16x8(*(const f32x4*)(ip + 32 * j),
                              *(const f32x4*)(ip + 32 * j + 4));
        u32x2 pk[8];
#pragma unroll
        for (int m = 0; m < 8; ++m) {
            f32x4 a = bi[m];
#pragma unroll
            for (int j = 0; j < 4; ++j) a = MFMA32(wa[m][j], xb[j], a);
            pk[m] = __builtin_bit_cast(u32x2, cvt_f16x4(a));
        }
        uint32_t* xpt = xp0 + (size_t)t * 1024;
#pragma unroll
        for (int q = 0; q < 4; ++q) {
            U22 qq = { pk[q], pk[q + 4] };   // paired layout {m=q, m=q+4}
            *(u32x4*)(xpt + q * 256) = __builtin_bit_cast(u32x4, qq);
        }
    }
}

// -------------------------------------------------------------------------
// Kernel 1: recurrence. Grid 4 (g), block 320 = 4 compute waves + 1 drain.
//   Compute wave w (on SIMD w): owns m = {w, w+4}. Per step: its own
//   B-frag bf[w] is a register concat of last step's pack (ZERO-latency
//   start on the matrix pipe); 3 ds_read_b128 fetch the other frags under
//   the MFMA issue; 8 MFMAs (2 chains x 4); pack; 1 ds_write_b128; 1 xp
//   ring load (depth 8). No global stores on compute waves.
//   Drain wave (SIMD 0): lags one step; 4 ds_read_b128 + 4 b128 stores,
//   4-deep store-reg rotation so store-ack WAR never blocks.
// MFMA floor/SIMD: 8 x 16cyc = 128 cyc/step (vs 512 for the 1-wave design).
// One LDS-only barrier per step; all 5 waves execute 4096 barriers.
// -------------------------------------------------------------------------
__global__ __launch_bounds__(320, 1)
void rec_kernel(const uint32_t* __restrict__ xp, const float* __restrict__ W1,
                uint32_t* __restrict__ hg) {
    const int g  = blockIdx.x;
    const int wv = threadIdx.x >> 6;   // 0..4
    const int l  = threadIdx.x & 63;
    const int c  = l & 15, u = l >> 4;

    __shared__ uint32_t hbuf[2][1024];   // [parity][kt*256 + 4l + i], 8 KB

    // h_0 = 0: zero parity-0 buffer
    for (int i = threadIdx.x; i < 1024; i += 320) hbuf[0][i] = 0;
    __syncthreads();

    if (wv < 4) {
        // ---- compute wave w ----
        const int w = wv;
        // A-frags for m = w (e=0) and m = w+4 (e=1), phiB K-gather:
        //   waH[e][kt] elem j = W1h[16m+c][ 64*(j>>2) + 16kt + 4u + (j&3) ]
        f16x8 waH[2][4];
#pragma unroll
        for (int e = 0; e < 2; ++e) {
            const float* wr = W1 + (16 * (w + 4 * e) + c) * 256;  // cols 0..127
#pragma unroll
            for (int kt = 0; kt < 4; ++kt)
                waH[e][kt] = cvt_f16x8(*(const f32x4*)(wr + 16 * kt + 4 * u),
                                       *(const f32x4*)(wr + 64 + 16 * kt + 4 * u));
        }

        const uint32_t* xpl = xp + ((size_t)g * T_LEN) * 1024 + w * 256 + 4 * l;

        // xp prefetch ring, depth 8 (one b128 per step)
        u32x4 xr[8];
#pragma unroll
        for (int p = 0; p < 8; ++p)
            xr[p] = *(const u32x4*)(xpl + (size_t)p * 1024);

        // own B-frag bf[w] = {pk[w], pk[w+4]} ; h_0 = 0
        f16x8 own;
        {
            const u32x4 z = {0, 0, 0, 0};
            own = __builtin_bit_cast(f16x8, z);
        }

#pragma unroll 1
        for (int t8 = 0; t8 < T_LEN; t8 += 8) {
#pragma unroll
            for (int p = 0; p < 8; ++p) {
                const int t   = t8 + p;
                const int par = p & 1;          // == t&1
                const uint32_t* rb = &hbuf[par][0];
                // other waves' frags (issued at barrier+0, land under MFMA)
                u32x4 r1 = *(const u32x4*)&rb[((w + 1) & 3) * 256 + 4 * l];
                u32x4 r2 = *(const u32x4*)&rb[((w + 2) & 3) * 256 + 4 * l];
                u32x4 r3 = *(const u32x4*)&rb[((w + 3) & 3) * 256 + 4 * l];
                // acc init from xp (paired: lo -> m=w, hi -> m=w+4)
                U22 xq = __builtin_bit_cast(U22, xr[p]);
                f32x4 a0 = unpk4(xq.a);
                f32x4 a1 = unpk4(xq.b);
                // kt = w first: fully local, no LDS wait
                a0 = MFMA32(waH[0][w], own, a0);
                a1 = MFMA32(waH[1][w], own, a1);
                f16x8 b1 = __builtin_bit_cast(f16x8, r1);
                a0 = MFMA32(waH[0][(w + 1) & 3], b1, a0);
                a1 = MFMA32(waH[1][(w + 1) & 3], b1, a1);
                f16x8 b2 = __builtin_bit_cast(f16x8, r2);
                a0 = MFMA32(waH[0][(w + 2) & 3], b2, a0);
                a1 = MFMA32(waH[1][(w + 2) & 3], b2, a1);
                f16x8 b3 = __builtin_bit_cast(f16x8, r3);
                a0 = MFMA32(waH[0][(w + 3) & 3], b3, a0);
                a1 = MFMA32(waH[1][(w + 3) & 3], b3, a1);
                // pack h_{t+1} pair; own bf for t+1 is the register concat
                u32x2 p0 = relu_pk(a0);
                u32x2 p1 = relu_pk(a1);
                U22 oq = { p0, p1 };
                own = __builtin_bit_cast(f16x8, oq);
                // publish own frag for the other waves (+ drain wave)
                *(u32x4*)&hbuf[par ^ 1][w * 256 + 4 * l] =
                    __builtin_bit_cast(u32x4, oq);
                // ring refill for t+8 (clamped tail; dummies unused)
                int tn = t + 8; if (tn > T_LEN - 1) tn = T_LEN - 1;
                xr[p] = *(const u32x4*)(xpl + (size_t)tn * 1024);
                LDS_BARRIER();
            }
        }
    } else {
        // ---- drain wave ----
        // During step-window t, hbuf[t&1] holds h_t (published at barrier
        // end of t-1). Drain stores h_t -> hg[t-1]. Store regs rotate 4-deep
        // (v[p&3]) so the WAR vmcnt wait targets 4-step-old acks (~free).
        uint32_t* hgp = hg + ((size_t)g * T_LEN) * 1024 + 4 * l;
        u32x4 v[4][4];
#pragma unroll 1
        for (int t8 = 0; t8 < T_LEN; t8 += 8) {
#pragma unroll
            for (int p = 0; p < 8; ++p) {
                const int t   = t8 + p;
                const int par = p & 1;
                if (t > 0) {
                    const int r = p & 3;
                    const uint32_t* rb = &hbuf[par][0];
#pragma unroll
                    for (int q = 0; q < 4; ++q)
                        v[r][q] = *(const u32x4*)&rb[q * 256 + 4 * l];
                    uint32_t* hp = hgp + (size_t)(t - 1) * 1024;
#pragma unroll
                    for (int q = 0; q < 4; ++q)
                        *(u32x4*)(hp + q * 256) = v[r][q];
                }
                LDS_BARRIER();   // lgkmcnt(0) drains our ds_reads before the
                                 // compute waves overwrite this buffer at t+1
            }
        }
        // final: h_T sits in hbuf[0] (T&1==0), published by the last barrier
        {
            const uint32_t* rb = &hbuf[0][0];
            u32x4 vf[4];
#pragma unroll
            for (int q = 0; q < 4; ++q)
                vf[q] = *(const u32x4*)&rb[q * 256 + 4 * l];
            uint32_t* hp = hgp + (size_t)(T_LEN - 1) * 1024;
#pragma unroll
            for (int q = 0; q < 4; ++q)
                *(u32x4*)(hp + q * 256) = vf[q];
        }
    }
}

// -------------------------------------------------------------------------
// Kernel 2: out[b,t,:] = relu(W2 . h_{t+1} + b2), K=16 MFMA.
// h frags read verbatim (C-frag == B-frag for 16x16x16 under phiC); paired
// layout: pk[s] lives at quarter q=s&3, half s>>2.
// Grid 2048 = g*512 + tc, block 64, 8 t per block.
// -------------------------------------------------------------------------
__global__ __launch_bounds__(64, 2)
void out_kernel(const uint32_t* __restrict__ hg, const float* __restrict__ W2,
                const float* __restrict__ b2, float* __restrict__ out) {
    const int bid = blockIdx.x;
    const int g   = bid >> 9;
    const int tc  = bid & 511;
    const int l   = threadIdx.x;
    const int c   = l & 15, u = l >> 4;

    f16x4 wa[8][8];
#pragma unroll
    for (int m = 0; m < 8; ++m) {
        const float* wr = W2 + (16 * m + c) * 128 + 4 * u;
#pragma unroll
        for (int s = 0; s < 8; ++s)
            wa[m][s] = cvt_f16x4(*(const f32x4*)(wr + 16 * s));
    }
    f32x4 bi[8];
#pragma unroll
    for (int m = 0; m < 8; ++m) bi[m] = *(const f32x4*)(b2 + 16 * m + 4 * u);

    const int t0 = tc * 8;
    const uint32_t* hg0 = hg + ((size_t)g * T_LEN) * 1024 + 4 * l;
    float* op0 = out + (size_t)(16 * g + c) * T_LEN * NHID + 4 * u;
#pragma unroll 1
    for (int tt = 0; tt < 8; ++tt) {
        const int t = t0 + tt;
        const uint32_t* hp = hg0 + (size_t)t * 1024;
        f16x4 hb[8];
#pragma unroll
        for (int s = 0; s < 8; ++s)
            hb[s] = __builtin_bit_cast(f16x4,
                        *(const u32x2*)(hp + (s & 3) * 256 + (s >> 2) * 2));
        f32x4 acc[8];
#pragma unroll
        for (int m = 0; m < 8; ++m) {
            f32x4 a = bi[m];
#pragma unroll
            for (int s = 0; s < 8; ++s) a = MFMA16(wa[m][s], hb[s], a);
            acc[m] = relu4(a);
        }
        float* op = op0 + (size_t)t * NHID;
#pragma unroll
        for (int m = 0; m < 8; ++m) *(f32x4*)(op + 16 * m) = acc[m];
    }
}

// -------------------------------------------------------------------------
extern "C" void kernel_launch(void* const* d_in, const int* in_sizes, int n_in,
                              void* d_out, int out_size, void* d_ws, size_t ws_size,
                              hipStream_t stream) {
    const float* input = (const float*)d_in[0];  // (64, 4096, 128) f32
    const float* W1    = (const float*)d_in[1];  // (128, 256) f32
    const float* b1    = (const float*)d_in[2];  // (128,) f32
    const float* W2    = (const float*)d_in[3];  // (128, 128) f32
    const float* b2    = (const float*)d_in[4];  // (128,) f32
    float*    out = (float*)d_out;
    uint32_t* xpb = (uint32_t*)d_out;            // xp scratch (64 MiB, f16-
                                                 // packed) in d_out; fully
                                                 // consumed by rec before
                                                 // out_kernel overwrites
    uint32_t* hgb = (uint32_t*)d_ws;             // h stream: 64 MiB in d_ws

    xproj_kernel<<<1024, 64, 0, stream>>>(input, W1, b1, xpb);
    rec_kernel  <<<4,   320, 0, stream>>>(xpb, W1, hgb);
    out_kernel  <<<2048, 64, 0, stream>>>(hgb, W2, b2, out);
}

// Round 5
// 1072.409 us; speedup vs baseline: 1.8722x; 1.0759x over previous
//
#include <hip/hip_runtime.h>
#include <stdint.h>

#define T_LEN 4096
#define NHID  128

typedef float    f32x4 __attribute__((ext_vector_type(4)));
typedef _Float16 f16x4 __attribute__((ext_vector_type(4)));
typedef _Float16 f16x8 __attribute__((ext_vector_type(8)));
typedef __fp16   h16x2 __attribute__((ext_vector_type(2)));
typedef uint32_t u32x2 __attribute__((ext_vector_type(2)));
typedef uint32_t u32x4 __attribute__((ext_vector_type(4)));

struct P2 { h16x2 p0, p1; };
struct P4 { h16x2 p0, p1, p2, p3; };
struct U22 { u32x2 a, b; };

static __device__ __forceinline__ f16x4 cvt_f16x4(f32x4 v) {
    P2 p;
    p.p0 = __builtin_amdgcn_cvt_pkrtz(v.x, v.y);
    p.p1 = __builtin_amdgcn_cvt_pkrtz(v.z, v.w);
    return __builtin_bit_cast(f16x4, p);
}
static __device__ __forceinline__ f16x8 cvt_f16x8(f32x4 a, f32x4 b) {
    P4 p;
    p.p0 = __builtin_amdgcn_cvt_pkrtz(a.x, a.y);
    p.p1 = __builtin_amdgcn_cvt_pkrtz(a.z, a.w);
    p.p2 = __builtin_amdgcn_cvt_pkrtz(b.x, b.y);
    p.p3 = __builtin_amdgcn_cvt_pkrtz(b.z, b.w);
    return __builtin_bit_cast(f16x8, p);
}
static __device__ __forceinline__ f32x4 relu4(f32x4 v) {
    v.x = fmaxf(v.x, 0.f); v.y = fmaxf(v.y, 0.f);
    v.z = fmaxf(v.z, 0.f); v.w = fmaxf(v.w, 0.f);
    return v;
}
// pack f32x4 -> 4 f16 (RTZ) then relu in f16 (identical result to relu-then-pack)
static __device__ __forceinline__ u32x2 relu_pk(f32x4 v) {
    P2 p;
    p.p0 = __builtin_amdgcn_cvt_pkrtz(v.x, v.y);
    p.p1 = __builtin_amdgcn_cvt_pkrtz(v.z, v.w);
    f16x4 h = __builtin_bit_cast(f16x4, p);
    const f16x4 z = {};
    h = __builtin_elementwise_max(h, z);   // 2x v_pk_max_f16
    return __builtin_bit_cast(u32x2, h);
}
static __device__ __forceinline__ f32x4 unpk4(u32x2 q) {
    f16x4 h = __builtin_bit_cast(f16x4, q);
    f32x4 r = { (float)h.x, (float)h.y, (float)h.z, (float)h.w };
    return r;
}
#define MFMA32(a, b, c) __builtin_amdgcn_mfma_f32_16x16x32_f16((a), (b), (c), 0, 0, 0)
#define MFMA16(a, b, c) __builtin_amdgcn_mfma_f32_16x16x16f16((a), (b), (c), 0, 0, 0)

// LDS-only barrier: drains LDS ops, leaves global (vmcnt) traffic in flight.
#define LDS_BARRIER()  asm volatile("s_waitcnt lgkmcnt(0)\n\ts_barrier" ::: "memory")
// plain barrier (drain wave: lgkm ordering enforced by its own data deps)
#define BARRIER_ONLY() asm volatile("s_barrier" ::: "memory")

// Layouts (per batch group g; lane l=(u<<4)|c, batch=16g+c):
//   phiC (C-frag / h / xp storage): unit(m,u,i) = 16m + 4u + i
//   phiB (W1h K-axis gather):  unit(kt,u,j) = 64*(j>>2) + 16kt + 4u + (j&3)
// B-frag[kt] of step t+1 == concat(pk[kt], pk[kt+4]) of step t's packed C
// output. Wave w owns m = {w, w+4}: bf[w] is FULLY LOCAL (register concat);
// 3 frags/step cross waves via LDS.
//
// xp (packed f16, in d_out): xp[(g*T+t)*1024 + q*256 + 4l + 0..3] (u32)
//   q-th u32x4 = { pk[q], pk[q+4] }
// hg (packed f16, in d_ws):  hg[(g*T+t)*1024 + q*256 + 4l + 0..3] (u32)
//   q-th u32x4 = { pk[q], pk[q+4] }   (h_{t+1} at index t)

// -------------------------------------------------------------------------
// Kernel 0: xp = input . W1x^T + b1 (K=32 MFMA), packed f16, paired layout.
// Grid 1024 = g*256 + tc, block 64, 16 t per block.
// -------------------------------------------------------------------------
__global__ __launch_bounds__(64, 2)
void xproj_kernel(const float* __restrict__ input, const float* __restrict__ W1,
                  const float* __restrict__ b1, uint32_t* __restrict__ xp) {
    const int bid = blockIdx.x;
    const int g   = bid >> 8;          // 0..3
    const int tc  = bid & 255;         // 0..255
    const int l   = threadIdx.x;
    const int c   = l & 15, u = l >> 4;

    // A-fragments of W1x (cols 128..255): A[m=c][k=32j+8u+0..7]
    f16x8 wa[8][4];
#pragma unroll
    for (int m = 0; m < 8; ++m) {
        const float* wr = W1 + (16 * m + c) * 256 + 128 + 8 * u;
#pragma unroll
        for (int j = 0; j < 4; ++j)
            wa[m][j] = cvt_f16x8(*(const f32x4*)(wr + 32 * j),
                                 *(const f32x4*)(wr + 32 * j + 4));
    }
    f32x4 bi[8];
#pragma unroll
    for (int m = 0; m < 8; ++m) bi[m] = *(const f32x4*)(b1 + 16 * m + 4 * u);

    const int t0 = tc * 16;
    const float* ip0 = input + (size_t)(16 * g + c) * T_LEN * NHID + 8 * u;
    uint32_t* xp0 = xp + ((size_t)g * T_LEN) * 1024 + 4 * l;
#pragma unroll 1
    for (int tt = 0; tt < 16; ++tt) {
        const int t = t0 + tt;
        const float* ip = ip0 + (size_t)t * NHID;
        f16x8 xb[4];
#pragma unroll
        for (int j = 0; j < 4; ++j)
            xb[j] = cvt_f16x8(*(const f32x4*)(ip + 32 * j),
                              *(const f32x4*)(ip + 32 * j + 4));
        u32x2 pk[8];
#pragma unroll
        for (int m = 0; m < 8; ++m) {
            f32x4 a = bi[m];
#pragma unroll
            for (int j = 0; j < 4; ++j) a = MFMA32(wa[m][j], xb[j], a);
            pk[m] = __builtin_bit_cast(u32x2, cvt_f16x4(a));
        }
        uint32_t* xpt = xp0 + (size_t)t * 1024;
#pragma unroll
        for (int q = 0; q < 4; ++q) {
            U22 qq = { pk[q], pk[q + 4] };   // paired layout {m=q, m=q+4}
            *(u32x4*)(xpt + q * 256) = __builtin_bit_cast(u32x4, qq);
        }
    }
}

// -------------------------------------------------------------------------
// Kernel 1: recurrence. Grid 4 (g), block 320 = 4 compute waves + 1 drain.
//   4-slot LDS h-ring (16 KB): at step t computes read slot t&3 (h_t),
//   write slot (t+1)&3 (h_{t+1}). A slot is overwritten only every 4 steps
//   -> the drain wave has a 2-window deadline and can use plain s_barrier.
//   Compute wave w (setprio 1): per step, 4 accumulator chains of depth 2
//   (a0a: kt=w local -> kt=w+2; a0b: kt=w+1 -> kt=w+3; same for a1*),
//   merged by v_add. xp unpack for step t+1 hoisted into step t's LDS
//   latency gap. 1 ds_write + 1 xp ring load (depth 8) per step.
//   Drain wave (setprio 0, shares SIMD with wave 0): works only on ODD
//   steps (stores h_t and h_{t-1}), 2-deep store-reg rotation.
// -------------------------------------------------------------------------
__global__ __launch_bounds__(320, 1)
void rec_kernel(const uint32_t* __restrict__ xp, const float* __restrict__ W1,
                uint32_t* __restrict__ hg) {
    const int g  = blockIdx.x;
    const int wv = threadIdx.x >> 6;   // 0..4
    const int l  = threadIdx.x & 63;
    const int c  = l & 15, u = l >> 4;

    __shared__ uint32_t hbuf[4][1024];   // 4-slot ring, 16 KB

    // h_0 = 0: zero slot 0
    for (int i = threadIdx.x; i < 1024; i += 320) hbuf[0][i] = 0;
    __syncthreads();

    if (wv < 4) {
        // ---- compute wave w ----
        __builtin_amdgcn_s_setprio(1);
        const int w = wv;
        // A-frags for m = w (e=0) and m = w+4 (e=1), phiB K-gather:
        //   waH[e][kt] elem j = W1h[16m+c][ 64*(j>>2) + 16kt + 4u + (j&3) ]
        f16x8 waH[2][4];
#pragma unroll
        for (int e = 0; e < 2; ++e) {
            const float* wr = W1 + (16 * (w + 4 * e) + c) * 256;  // cols 0..127
#pragma unroll
            for (int kt = 0; kt < 4; ++kt)
                waH[e][kt] = cvt_f16x8(*(const f32x4*)(wr + 16 * kt + 4 * u),
                                       *(const f32x4*)(wr + 64 + 16 * kt + 4 * u));
        }

        const uint32_t* xpl = xp + ((size_t)g * T_LEN) * 1024 + w * 256 + 4 * l;

        // xp prefetch ring, depth 8 (one b128 per step)
        u32x4 xr[8];
#pragma unroll
        for (int p = 0; p < 8; ++p)
            xr[p] = *(const u32x4*)(xpl + (size_t)p * 1024);

        // own B-frag bf[w] = {pk[w], pk[w+4]} ; h_0 = 0
        f16x8 own;
        {
            const u32x4 z = {0, 0, 0, 0};
            own = __builtin_bit_cast(f16x8, z);
        }
        // pre-unpacked xp accumulator init for the CURRENT step
        f32x4 xf0, xf1;
        {
            U22 xq = __builtin_bit_cast(U22, xr[0]);
            xf0 = unpk4(xq.a);
            xf1 = unpk4(xq.b);
        }
        const f32x4 zf = { 0.f, 0.f, 0.f, 0.f };
        const int k1 = (w + 1) & 3, k2 = (w + 2) & 3, k3 = (w + 3) & 3;

#pragma unroll 1
        for (int t8 = 0; t8 < T_LEN; t8 += 8) {
#pragma unroll
            for (int p = 0; p < 8; ++p) {
                const int t = t8 + p;
                const uint32_t* rb = &hbuf[p & 3][0];   // slot t&3 = h_t
                // remote frags: issue at barrier+0, land under local MFMAs
                u32x4 r1 = *(const u32x4*)&rb[k1 * 256 + 4 * l];
                u32x4 r2 = *(const u32x4*)&rb[k2 * 256 + 4 * l];
                u32x4 r3 = *(const u32x4*)&rb[k3 * 256 + 4 * l];
                // local chain heads (no LDS dependency)
                f32x4 a0a = MFMA32(waH[0][w], own, xf0);
                f32x4 a1a = MFMA32(waH[1][w], own, xf1);
                // hoist next step's xp unpack into the LDS latency gap
                {
                    U22 xq = __builtin_bit_cast(U22, xr[(p + 1) & 7]);
                    xf0 = unpk4(xq.a);
                    xf1 = unpk4(xq.b);
                }
                // 4 chains of depth 2
                f16x8 b1 = __builtin_bit_cast(f16x8, r1);
                f32x4 a0b = MFMA32(waH[0][k1], b1, zf);
                f32x4 a1b = MFMA32(waH[1][k1], b1, zf);
                f16x8 b2 = __builtin_bit_cast(f16x8, r2);
                a0a = MFMA32(waH[0][k2], b2, a0a);
                a1a = MFMA32(waH[1][k2], b2, a1a);
                f16x8 b3 = __builtin_bit_cast(f16x8, r3);
                a0b = MFMA32(waH[0][k3], b3, a0b);
                a1b = MFMA32(waH[1][k3], b3, a1b);
                // merge, pack h_{t+1}; own bf for t+1 is the register concat
                u32x2 p0 = relu_pk(a0a + a0b);
                u32x2 p1 = relu_pk(a1a + a1b);
                U22 oq = { p0, p1 };
                own = __builtin_bit_cast(f16x8, oq);
                // publish own frag into slot (t+1)&3
                *(u32x4*)&hbuf[(p + 1) & 3][w * 256 + 4 * l] =
                    __builtin_bit_cast(u32x4, oq);
                // ring refill for t+8 (clamped tail; dummies unused)
                int tn = t + 8; if (tn > T_LEN - 1) tn = T_LEN - 1;
                xr[p] = *(const u32x4*)(xpl + (size_t)tn * 1024);
                LDS_BARRIER();
            }
        }
    } else {
        // ---- drain wave (setprio 0 default) ----
        // Odd step t: store h_t -> hg[t-1] and h_{t-1} -> hg[t-2] (skip at
        // t==1). Slots t&3 and (t-1)&3 are not being written this window.
        // Read->store data deps force the lgkm waits; barrier is plain.
        uint32_t* hgp = hg + ((size_t)g * T_LEN) * 1024 + 4 * l;
        u32x4 v[2][8];
#pragma unroll 1
        for (int t8 = 0; t8 < T_LEN; t8 += 8) {
#pragma unroll
            for (int p = 0; p < 8; ++p) {
                const int t = t8 + p;
                if (p & 1) {
                    const int r = (p >> 1) & 1;
                    const uint32_t* rbA = &hbuf[p & 3][0];        // h_t
                    const uint32_t* rbB = &hbuf[(p - 1) & 3][0];  // h_{t-1}
#pragma unroll
                    for (int q = 0; q < 4; ++q)
                        v[r][q] = *(const u32x4*)&rbA[q * 256 + 4 * l];
#pragma unroll
                    for (int q = 0; q < 4; ++q)
                        v[r][4 + q] = *(const u32x4*)&rbB[q * 256 + 4 * l];
                    uint32_t* hpA = hgp + (size_t)(t - 1) * 1024;
#pragma unroll
                    for (int q = 0; q < 4; ++q)
                        *(u32x4*)(hpA + q * 256) = v[r][q];
                    if (t > 1) {
                        uint32_t* hpB = hgp + (size_t)(t - 2) * 1024;
#pragma unroll
                        for (int q = 0; q < 4; ++q)
                            *(u32x4*)(hpB + q * 256) = v[r][4 + q];
                    }
                }
                BARRIER_ONLY();
            }
        }
        // final: h_T in slot T&3 == 0, published by the last barrier
        {
            const uint32_t* rb = &hbuf[0][0];
            u32x4 vf[4];
#pragma unroll
            for (int q = 0; q < 4; ++q)
                vf[q] = *(const u32x4*)&rb[q * 256 + 4 * l];
            uint32_t* hp = hgp + (size_t)(T_LEN - 1) * 1024;
#pragma unroll
            for (int q = 0; q < 4; ++q)
                *(u32x4*)(hp + q * 256) = vf[q];
        }
    }
}

// -------------------------------------------------------------------------
// Kernel 2: out[b,t,:] = relu(W2 . h_{t+1} + b2), K=16 MFMA.
// h frags read verbatim (C-frag == B-frag for 16x16x16 under phiC); paired
// layout: pk[s] lives at quarter q=s&3, half s>>2.
// Grid 2048 = g*512 + tc, block 64, 8 t per block.
// -------------------------------------------------------------------------
__global__ __launch_bounds__(64, 2)
void out_kernel(const uint32_t* __restrict__ hg, const float* __restrict__ W2,
                const float* __restrict__ b2, float* __restrict__ out) {
    const int bid = blockIdx.x;
    const int g   = bid >> 9;
    const int tc  = bid & 511;
    const int l   = threadIdx.x;
    const int c   = l & 15, u = l >> 4;

    f16x4 wa[8][8];
#pragma unroll
    for (int m = 0; m < 8; ++m) {
        const float* wr = W2 + (16 * m + c) * 128 + 4 * u;
#pragma unroll
        for (int s = 0; s < 8; ++s)
            wa[m][s] = cvt_f16x4(*(const f32x4*)(wr + 16 * s));
    }
    f32x4 bi[8];
#pragma unroll
    for (int m = 0; m < 8; ++m) bi[m] = *(const f32x4*)(b2 + 16 * m + 4 * u);

    const int t0 = tc * 8;
    const uint32_t* hg0 = hg + ((size_t)g * T_LEN) * 1024 + 4 * l;
    float* op0 = out + (size_t)(16 * g + c) * T_LEN * NHID + 4 * u;
#pragma unroll 1
    for (int tt = 0; tt < 8; ++tt) {
        const int t = t0 + tt;
        const uint32_t* hp = hg0 + (size_t)t * 1024;
        f16x4 hb[8];
#pragma unroll
        for (int s = 0; s < 8; ++s)
            hb[s] = __builtin_bit_cast(f16x4,
                        *(const u32x2*)(hp + (s & 3) * 256 + (s >> 2) * 2));
        f32x4 acc[8];
#pragma unroll
        for (int m = 0; m < 8; ++m) {
            f32x4 a = bi[m];
#pragma unroll
            for (int s = 0; s < 8; ++s) a = MFMA16(wa[m][s], hb[s], a);
            acc[m] = relu4(a);
        }
        float* op = op0 + (size_t)t * NHID;
#pragma unroll
        for (int m = 0; m < 8; ++m) *(f32x4*)(op + 16 * m) = acc[m];
    }
}

// -------------------------------------------------------------------------
extern "C" void kernel_launch(void* const* d_in, const int* in_sizes, int n_in,
                              void* d_out, int out_size, void* d_ws, size_t ws_size,
                              hipStream_t stream) {
    const float* input = (const float*)d_in[0];  // (64, 4096, 128) f32
    const float* W1    = (const float*)d_in[1];  // (128, 256) f32
    const float* b1    = (const float*)d_in[2];  // (128,) f32
    const float* W2    = (const float*)d_in[3];  // (128, 128) f32
    const float* b2    = (const float*)d_in[4];  // (128,) f32
    float*    out = (float*)d_out;
    uint32_t* xpb = (uint32_t*)d_out;            // xp scratch (64 MiB, f16-
                                                 // packed) in d_out; fully
                                                 // consumed by rec before
                                                 // out_kernel overwrites
    uint32_t* hgb = (uint32_t*)d_ws;             // h stream: 64 MiB in d_ws

    xproj_kernel<<<1024, 64, 0, stream>>>(input, W1, b1, xpb);
    rec_kernel  <<<4,   320, 0, stream>>>(xpb, W1, hgb);
    out_kernel  <<<2048, 64, 0, stream>>>(hgb, W2, b2, out);
}